// Round 10
// baseline (234.038 us; speedup 1.0000x reference)
//
#include <hip/hip_runtime.h>
#include <hip/hip_bf16.h>

// Problem constants (match reference)
#define NNODE_DIN 128
#define NNODE_DOUT 128
#define DEG 48
#define TOPK 32

typedef _Float16 halfx8 __attribute__((ext_vector_type(8)));
typedef unsigned short ushortx8 __attribute__((ext_vector_type(8)));
typedef float floatx4 __attribute__((ext_vector_type(4)));

__device__ inline unsigned short f2h(float f) {
    _Float16 h = (_Float16)f;
    return __builtin_bit_cast(unsigned short, h);
}
__device__ inline float h2f(unsigned short u) {
    return (float)__builtin_bit_cast(_Float16, u);
}
// Raw transcendentals: proven correct in rounds 1-9 (absmax unchanged).
__device__ inline float fast_sqrt(float x) {
    float r; asm("v_sqrt_f32 %0, %1" : "=v"(r) : "v"(x)); return r;
}
__device__ inline float fast_exp(float x) {  // e^x, x <= 0 here (no overflow path)
    float t = x * 1.44269504088896341f;
    float r; asm("v_exp_f32 %0, %1" : "=v"(r) : "v"(t)); return r;
}
__device__ inline float fast_rcp(float x) {
    float r; asm("v_rcp_f32 %0, %1" : "=v"(r) : "v"(x)); return r;
}

// ---------------------------------------------------------------------------
// Kernel 0: pre-swizzle W^T into split-FP16 MFMA B-fragments (frozen).
// ---------------------------------------------------------------------------
__global__ __launch_bounds__(256) void k0_wprep(
    const float* __restrict__ w, unsigned short* __restrict__ wth,
    unsigned short* __restrict__ wtl) {
    int tid = blockIdx.x * 256 + threadIdx.x;  // 0..2047
    int lane = tid & 63;
    int kt = (tid >> 6) & 3;
    int nt = tid >> 8;
    int m = lane & 15, q = lane >> 4;
    int nn = nt * 16 + m;
    int k0 = kt * 32 + q * 8;
    ushortx8 uh, ul;
#pragma unroll
    for (int e = 0; e < 8; ++e) {
        float v = w[(size_t)(k0 + e) * 128 + nn];
        unsigned short h = f2h(v);
        uh[e] = h;
        ul[e] = f2h(v - h2f(h));
    }
    *(ushortx8*)(wth + tid * 8) = uh;
    *(ushortx8*)(wtl + tid * 8) = ul;
}

// ---------------------------------------------------------------------------
// Kernel 1: x = feat @ W via split-FP16 MFMA. Round-6 shape (best measured
// residue; round-7 4-wave split regressed it). FROZEN.
// ---------------------------------------------------------------------------
__global__ __launch_bounds__(64, 4) void k1_mfma(
    const float* __restrict__ feat, const unsigned short* __restrict__ wth,
    const unsigned short* __restrict__ wtl, unsigned short* __restrict__ xf,
    int n) {
    __shared__ float s_x[16 * 132];
    int l = threadIdx.x;
    int m = l & 15, q = l >> 4;
    int r0 = blockIdx.x * 16;

    halfx8 ah[4], al[4];
#pragma unroll
    for (int kt = 0; kt < 4; ++kt) {
        float vv[8];
        if (r0 + m < n) {
            const float* src = feat + (size_t)(r0 + m) * 128 + kt * 32 + q * 8;
            float4 v0 = *(const float4*)src;
            float4 v1 = *(const float4*)(src + 4);
            vv[0] = v0.x; vv[1] = v0.y; vv[2] = v0.z; vv[3] = v0.w;
            vv[4] = v1.x; vv[5] = v1.y; vv[6] = v1.z; vv[7] = v1.w;
        } else {
#pragma unroll
            for (int e = 0; e < 8; ++e) vv[e] = 0.0f;
        }
        ushortx8 uh, ul;
#pragma unroll
        for (int e = 0; e < 8; ++e) {
            unsigned short h = f2h(vv[e]);
            uh[e] = h;
            ul[e] = f2h(vv[e] - h2f(h));
        }
        ah[kt] = __builtin_bit_cast(halfx8, uh);
        al[kt] = __builtin_bit_cast(halfx8, ul);
    }

#pragma unroll 2
    for (int nt = 0; nt < 8; ++nt) {
        floatx4 a = (floatx4){0.f, 0.f, 0.f, 0.f};
#pragma unroll
        for (int kt = 0; kt < 4; ++kt) {
            int fo = ((nt * 4 + kt) * 64 + l) * 8;
            halfx8 bh = *(const halfx8*)(wth + fo);
            halfx8 bl = *(const halfx8*)(wtl + fo);
            a = __builtin_amdgcn_mfma_f32_16x16x32_f16(ah[kt], bh, a, 0, 0, 0);
            a = __builtin_amdgcn_mfma_f32_16x16x32_f16(ah[kt], bl, a, 0, 0, 0);
            a = __builtin_amdgcn_mfma_f32_16x16x32_f16(al[kt], bh, a, 0, 0, 0);
        }
#pragma unroll
        for (int r = 0; r < 4; ++r)
            s_x[(q * 4 + r) * 132 + nt * 16 + m] = a[r];
    }
    __syncthreads();

#pragma unroll
    for (int rr = 0; rr < 2; ++rr) {
        int row = rr * 8 + (l >> 3);
        int c0 = (l & 7) * 16;
        if (r0 + row < n) {
            float vv[16];
#pragma unroll
            for (int j = 0; j < 4; ++j) {
                float4 v = *(const float4*)&s_x[row * 132 + c0 + j * 4];
                vv[j * 4 + 0] = v.x; vv[j * 4 + 1] = v.y;
                vv[j * 4 + 2] = v.z; vv[j * 4 + 3] = v.w;
            }
            unsigned u[8];
#pragma unroll
            for (int p = 0; p < 8; ++p) {
                u[p] = (unsigned)f2h(vv[2 * p]) | ((unsigned)f2h(vv[2 * p + 1]) << 16);
            }
            size_t off = (size_t)(r0 + row) * 128 + c0;
            *(uint4*)(xf + off) = make_uint4(u[0], u[1], u[2], u[3]);
            *(uint4*)(xf + off + 8) = make_uint4(u[4], u[5], u[6], u[7]);
        }
    }
}

// ---------------------------------------------------------------------------
// Kernel 2: ROUND-10 — LDS-INSTRUCTION-MINIMIZED. Theory: per-node budget is
// ~1130 CU-cycles; counted LDS instructions (topk 49 uniform ds_reads, 24
// b128 staging ops, 64 ds_read_u16 in G, E/F misc) cost ~950-1180 LDS-pipe
// cycles -> the single per-CU LDS pipe is the saturated resource (uniquely
// explains occupancy/coalescing/conflict invariance of rounds 8-9).
// Changes (k2 logic identical, movement restructured):
//   1. topk in REGISTERS via __builtin_amdgcn_readlane (zero LDS in loop).
//   2. gather in direct MFMA layout (r8 mapping): Hown kept in registers,
//      only Hoth is re-read from LDS (8 b128/node instead of 16).
//   3. G from registers: omega[own row] * Hown, 2-level shfl_xor(8),(4)
//      m-reduction (r3-proven), 8 masked b128 stores/wave -> s_red[8][132],
//      final 8 b32 reads/thread. Replaces 64 ds_read_u16 + cvt chain.
// ---------------------------------------------------------------------------
__global__ __launch_bounds__(128, 4) void k2_conv(
    const float* __restrict__ ew, const int* __restrict__ nbr,
    const float* __restrict__ bias, const unsigned short* __restrict__ xf,
    float* __restrict__ outp, int n) {
    __shared__ float s_tw[32];
    __shared__ int s_id[32];
    __shared__ float s_diag[32];
    __shared__ float s_dist[32];
    __shared__ float s_omega[32];
    __shared__ float s_red[8][132];       // 2 waves x 4 m-classes x 128 (+pad)
    __shared__ _Float16 s_rows[32][136];  // padded stride (r7-proven)

    int i = blockIdx.x;
    int t = threadIdx.x;
    int w = t >> 6;   // wave 0..1
    int l = t & 63;

    // A+B: wave 0 only, all in registers. Lane j holds candidate j (48
    // neighbors + self at j=48); rank computed with readlane broadcasts
    // (exact jax.lax.top_k tie semantics: rank = #{t2: w>wj or (==, t2<j)}).
    if (w == 0) {
        float wj = -1.0f;  // sentinel for lanes 49-63 (never read/stored)
        int nbv = 0;
        if (l < DEG) {
            wj = ew[(size_t)i * DEG + l];
            nbv = nbr[(size_t)i * DEG + l];
        } else if (l == DEG) {
            wj = 1.0f;
            nbv = i;
        }
        int rank = 0;
#pragma unroll
        for (int t2 = 0; t2 <= DEG; ++t2) {
            int wti = __builtin_amdgcn_readlane(__builtin_bit_cast(int, wj), t2);
            float wt = __builtin_bit_cast(float, wti);
            rank += ((wt > wj) || ((wt == wj) && (t2 < l))) ? 1 : 0;
        }
        if (l <= DEG && rank < TOPK) {
            s_tw[rank] = wj;
            s_id[rank] = nbv;
        }
    }
    __syncthreads();

    // C: gather in direct MFMA layout (r8 mapping — r9 proved lane mapping
    // is time-neutral, so choose the register-friendly one). Wave w owns
    // rows [16w, 16w+16); lane (m,q) fetches row s_id[a0+m], slice q*8+kt*32.
    int m = l & 15;
    int q = l >> 4;
    int a0 = w * 16;
    int o0 = 16 - a0;
    int rowg = s_id[a0 + m];
    const _Float16* gp = (const _Float16*)xf + (size_t)rowg * 128 + q * 8;

    halfx8 Hown[4];
#pragma unroll
    for (int kt = 0; kt < 4; ++kt) Hown[kt] = *(const halfx8*)(gp + kt * 32);
#pragma unroll
    for (int kt = 0; kt < 4; ++kt)
        *(halfx8*)&s_rows[a0 + m][kt * 32 + q * 8] = Hown[kt];
    __syncthreads();

    // D: only the OTHER wave's rows come from LDS; own rows are registers.
    halfx8 Hoth[4];
#pragma unroll
    for (int kt = 0; kt < 4; ++kt)
        Hoth[kt] = *(const halfx8*)&s_rows[o0 + m][kt * 32 + q * 8];

    floatx4 accO = (floatx4){0.f, 0.f, 0.f, 0.f};  // G[a0+i][a0+j]
    floatx4 accX = (floatx4){0.f, 0.f, 0.f, 0.f};  // G[a0+i][o0+j]
#pragma unroll
    for (int kt = 0; kt < 4; ++kt) {
        accO = __builtin_amdgcn_mfma_f32_16x16x32_f16(Hown[kt], Hown[kt], accO, 0, 0, 0);
        accX = __builtin_amdgcn_mfma_f32_16x16x32_f16(Hown[kt], Hoth[kt], accX, 0, 0, 0);
    }

    // D2: diagonal from own quadrant (row==col -> d2_aa == 0 exactly)
    if (q == (m >> 2)) {
        s_diag[a0 + m] = accO[m & 3];
    }
    __syncthreads();

    // E: dist[a] = sum over all 32 b of tw[b]*sqrt(d2>0 ? d2 : 0), a in own 16
    {
        float dbO = s_diag[a0 + m];
        float dbX = s_diag[o0 + m];
        float twO = s_tw[a0 + m];
        float twX = s_tw[o0 + m];
#pragma unroll
        for (int r = 0; r < 4; ++r) {
            int a = a0 + q * 4 + r;
            float da = s_diag[a];
            float d2o = da + dbO - 2.0f * accO[r];
            float d2x = da + dbX - 2.0f * accX[r];
            float t0 = (d2o > 0.0f) ? fast_sqrt(d2o) : 0.0f;
            float t1 = (d2x > 0.0f) ? fast_sqrt(d2x) : 0.0f;
            float v = twO * t0 + twX * t1;
            v += __shfl_xor(v, 1);
            v += __shfl_xor(v, 2);
            v += __shfl_xor(v, 4);
            v += __shfl_xor(v, 8);
            if (m == 0) s_dist[a] = v;
        }
    }
    __syncthreads();

    // F: omega = exp(-dist - max(-dist)) * tw, normalized (wave 0 computes)
    if (w == 0) {
        int k32 = l & 31;
        float s = s_dist[k32];
        float mn = s;
        mn = fminf(mn, __shfl_xor(mn, 1));
        mn = fminf(mn, __shfl_xor(mn, 2));
        mn = fminf(mn, __shfl_xor(mn, 4));
        mn = fminf(mn, __shfl_xor(mn, 8));
        mn = fminf(mn, __shfl_xor(mn, 16));
        float e = fast_exp(mn - s) * s_tw[k32];
        float sum = e;
        sum += __shfl_xor(sum, 1);
        sum += __shfl_xor(sum, 2);
        sum += __shfl_xor(sum, 4);
        sum += __shfl_xor(sum, 8);
        sum += __shfl_xor(sum, 16);
        float om = e * fast_rcp(sum);
        if (l < 32) s_omega[l] = om;
    }
    __syncthreads();

    // G: from registers. Lane (m,q) contributes omega[a0+m]*Hown slices;
    // 2-level shfl_xor(8),(4) reduces over m to 4 m-classes (r3-proven),
    // masked b128 stores to s_red[w*4+mclass]; final: 8 b32 reads/thread.
    {
        float om = s_omega[a0 + m];
#pragma unroll
        for (int kt = 0; kt < 4; ++kt) {
            float p[8];
#pragma unroll
            for (int e = 0; e < 8; ++e) p[e] = om * (float)Hown[kt][e];
#pragma unroll
            for (int e = 0; e < 8; ++e) {
                p[e] += __shfl_xor(p[e], 8);
                p[e] += __shfl_xor(p[e], 4);
            }
            if (m < 4) {  // lane (q, m) holds sum over {m, m+4, m+8, m+12}
                float* dst = &s_red[w * 4 + m][kt * 32 + q * 8];
                *(float4*)dst = make_float4(p[0], p[1], p[2], p[3]);
                *(float4*)(dst + 4) = make_float4(p[4], p[5], p[6], p[7]);
            }
        }
    }
    __syncthreads();

    // Final: thread t sums the 8 partial rows for its column + bias.
    {
        float o = bias[t];
#pragma unroll
        for (int r = 0; r < 8; ++r) o += s_red[r][t];
        outp[(size_t)i * 128 + t] = o;
    }
}

extern "C" void kernel_launch(void* const* d_in, const int* in_sizes, int n_in,
                              void* d_out, int out_size, void* d_ws, size_t ws_size,
                              hipStream_t stream) {
    const float* feat = (const float*)d_in[0];
    const float* ew = (const float*)d_in[1];
    const float* weight = (const float*)d_in[2];
    const float* bias = (const float*)d_in[3];
    const int* nbr = (const int*)d_in[4];
    float* outp = (float*)d_out;
    int n = in_sizes[0] / NNODE_DIN;  // 50000

    unsigned short* xf = (unsigned short*)d_ws;            // n x 128 fp16
    unsigned short* wth = xf + (size_t)n * NNODE_DOUT;     // 2048 frags x 16B
    unsigned short* wtl = wth + 2048 * 8;

    hipLaunchKernelGGL(k0_wprep, dim3(8), dim3(256), 0, stream, weight, wth, wtl);
    int grid1 = (n + 15) / 16;
    hipLaunchKernelGGL(k1_mfma, dim3(grid1), dim3(64), 0, stream, feat, wth, wtl, xf, n);
    hipLaunchKernelGGL(k2_conv, dim3(n), dim3(128), 0, stream, ew, nbr, bias, xf, outp, n);
}

// Round 11
// 176.661 us; speedup vs baseline: 1.3248x; 1.3248x over previous
//
#include <hip/hip_runtime.h>
#include <hip/hip_bf16.h>

// Problem constants (match reference)
#define NNODE_DIN 128
#define NNODE_DOUT 128
#define DEG 48
#define TOPK 32

typedef _Float16 halfx8 __attribute__((ext_vector_type(8)));
typedef unsigned short ushortx8 __attribute__((ext_vector_type(8)));
typedef float floatx4 __attribute__((ext_vector_type(4)));

__device__ inline unsigned short f2h(float f) {
    _Float16 h = (_Float16)f;
    return __builtin_bit_cast(unsigned short, h);
}
__device__ inline float h2f(unsigned short u) {
    return (float)__builtin_bit_cast(_Float16, u);
}
// Raw transcendentals: proven correct in rounds 1-10 (absmax unchanged).
__device__ inline float fast_sqrt(float x) {
    float r; asm("v_sqrt_f32 %0, %1" : "=v"(r) : "v"(x)); return r;
}
__device__ inline float fast_exp(float x) {  // e^x, x <= 0 here (no overflow path)
    float t = x * 1.44269504088896341f;
    float r; asm("v_exp_f32 %0, %1" : "=v"(r) : "v"(t)); return r;
}
__device__ inline float fast_rcp(float x) {
    float r; asm("v_rcp_f32 %0, %1" : "=v"(r) : "v"(x)); return r;
}

// ---------------------------------------------------------------------------
// Kernel 0: pre-swizzle W^T into split-FP16 MFMA B-fragments (frozen).
// ---------------------------------------------------------------------------
__global__ __launch_bounds__(256) void k0_wprep(
    const float* __restrict__ w, unsigned short* __restrict__ wth,
    unsigned short* __restrict__ wtl) {
    int tid = blockIdx.x * 256 + threadIdx.x;  // 0..2047
    int lane = tid & 63;
    int kt = (tid >> 6) & 3;
    int nt = tid >> 8;
    int m = lane & 15, q = lane >> 4;
    int nn = nt * 16 + m;
    int k0 = kt * 32 + q * 8;
    ushortx8 uh, ul;
#pragma unroll
    for (int e = 0; e < 8; ++e) {
        float v = w[(size_t)(k0 + e) * 128 + nn];
        unsigned short h = f2h(v);
        uh[e] = h;
        ul[e] = f2h(v - h2f(h));
    }
    *(ushortx8*)(wth + tid * 8) = uh;
    *(ushortx8*)(wtl + tid * 8) = ul;
}

// ---------------------------------------------------------------------------
// Kernel 1: x = feat @ W via split-FP16 MFMA. Round-6 shape (best measured
// residue; round-7 4-wave split regressed it). FROZEN.
// ---------------------------------------------------------------------------
__global__ __launch_bounds__(64, 4) void k1_mfma(
    const float* __restrict__ feat, const unsigned short* __restrict__ wth,
    const unsigned short* __restrict__ wtl, unsigned short* __restrict__ xf,
    int n) {
    __shared__ float s_x[16 * 132];
    int l = threadIdx.x;
    int m = l & 15, q = l >> 4;
    int r0 = blockIdx.x * 16;

    halfx8 ah[4], al[4];
#pragma unroll
    for (int kt = 0; kt < 4; ++kt) {
        float vv[8];
        if (r0 + m < n) {
            const float* src = feat + (size_t)(r0 + m) * 128 + kt * 32 + q * 8;
            float4 v0 = *(const float4*)src;
            float4 v1 = *(const float4*)(src + 4);
            vv[0] = v0.x; vv[1] = v0.y; vv[2] = v0.z; vv[3] = v0.w;
            vv[4] = v1.x; vv[5] = v1.y; vv[6] = v1.z; vv[7] = v1.w;
        } else {
#pragma unroll
            for (int e = 0; e < 8; ++e) vv[e] = 0.0f;
        }
        ushortx8 uh, ul;
#pragma unroll
        for (int e = 0; e < 8; ++e) {
            unsigned short h = f2h(vv[e]);
            uh[e] = h;
            ul[e] = f2h(vv[e] - h2f(h));
        }
        ah[kt] = __builtin_bit_cast(halfx8, uh);
        al[kt] = __builtin_bit_cast(halfx8, ul);
    }

#pragma unroll 2
    for (int nt = 0; nt < 8; ++nt) {
        floatx4 a = (floatx4){0.f, 0.f, 0.f, 0.f};
#pragma unroll
        for (int kt = 0; kt < 4; ++kt) {
            int fo = ((nt * 4 + kt) * 64 + l) * 8;
            halfx8 bh = *(const halfx8*)(wth + fo);
            halfx8 bl = *(const halfx8*)(wtl + fo);
            a = __builtin_amdgcn_mfma_f32_16x16x32_f16(ah[kt], bh, a, 0, 0, 0);
            a = __builtin_amdgcn_mfma_f32_16x16x32_f16(ah[kt], bl, a, 0, 0, 0);
            a = __builtin_amdgcn_mfma_f32_16x16x32_f16(al[kt], bh, a, 0, 0, 0);
        }
#pragma unroll
        for (int r = 0; r < 4; ++r)
            s_x[(q * 4 + r) * 132 + nt * 16 + m] = a[r];
    }
    __syncthreads();

#pragma unroll
    for (int rr = 0; rr < 2; ++rr) {
        int row = rr * 8 + (l >> 3);
        int c0 = (l & 7) * 16;
        if (r0 + row < n) {
            float vv[16];
#pragma unroll
            for (int j = 0; j < 4; ++j) {
                float4 v = *(const float4*)&s_x[row * 132 + c0 + j * 4];
                vv[j * 4 + 0] = v.x; vv[j * 4 + 1] = v.y;
                vv[j * 4 + 2] = v.z; vv[j * 4 + 3] = v.w;
            }
            unsigned u[8];
#pragma unroll
            for (int p = 0; p < 8; ++p) {
                u[p] = (unsigned)f2h(vv[2 * p]) | ((unsigned)f2h(vv[2 * p + 1]) << 16);
            }
            size_t off = (size_t)(r0 + row) * 128 + c0;
            *(uint4*)(xf + off) = make_uint4(u[0], u[1], u[2], u[3]);
            *(uint4*)(xf + off + 8) = make_uint4(u[4], u[5], u[6], u[7]);
        }
    }
}

// ---------------------------------------------------------------------------
// Kernel 2: ROUND-11 = ROUND-8 STRUCTURE (best: 92us, register-Hown) + ONE
// change: TOPK IN REGISTERS. Post-mortem of r10: __shfl_xor lowers to
// ds_swizzle/ds_permute — SAME LDS pipe — so r10 relocated ~100 LDS-class
// ops instead of removing them, grew LDS (occ 79->58), and regressed.
// LDS-pipe accounting of r8 (~220 LDS-class ops/node ~= 950-1250 pipe cycles
// vs the 1130-cycle/node budget) remains the only model consistent with all
// nulls (occupancy, coalescing, conflicts). This round REMOVES ops: the
// topk rank loop's 49 uniform ds_reads become readlane broadcasts (scalar
// path, r10-proven numerics); s_w/s_nb LDS arrays deleted. Both waves
// compute the rank redundantly in parallel (no wave-0 stall); wave 0 writes
// the 32 s_tw/s_id slots. -49 LDS ops/node (~22%), LDS down to ~9.3 KB.
// ---------------------------------------------------------------------------
__global__ __launch_bounds__(128, 4) void k2_conv(
    const float* __restrict__ ew, const int* __restrict__ nbr,
    const float* __restrict__ bias, const unsigned short* __restrict__ xf,
    float* __restrict__ outp, int n) {
    __shared__ float s_tw[32];
    __shared__ int s_id[32];
    __shared__ float s_diag[32];
    __shared__ float s_dist[32];
    __shared__ float s_omega[32];
    __shared__ _Float16 s_rows[32][136];  // padded stride (r7-proven, 0 confl)

    int i = blockIdx.x;
    int t = threadIdx.x;
    int w = t >> 6;   // wave 0..1
    int l = t & 63;

    // A+B: register top-k (exact jax.lax.top_k tie semantics). Lane j of
    // each wave holds candidate j (48 neighbors + self at j=48); rank via
    // readlane broadcasts — zero LDS ops. Both waves compute (parallel,
    // no idle); wave 0 writes the 32 slots.
    {
        float wj = -1.0f;  // sentinel for lanes 49-63 (rank >= 49, never written)
        int nbv = 0;
        if (l < DEG) {
            wj = ew[(size_t)i * DEG + l];
            nbv = nbr[(size_t)i * DEG + l];
        } else if (l == DEG) {
            wj = 1.0f;
            nbv = i;
        }
        int rank = 0;
#pragma unroll
        for (int t2 = 0; t2 <= DEG; ++t2) {
            int wti = __builtin_amdgcn_readlane(__builtin_bit_cast(int, wj), t2);
            float wt = __builtin_bit_cast(float, wti);
            rank += ((wt > wj) || ((wt == wj) && (t2 < l))) ? 1 : 0;
        }
        if (w == 0 && l <= DEG && rank < TOPK) {
            s_tw[rank] = wj;
            s_id[rank] = nbv;
        }
    }
    __syncthreads();

    // C: gather in direct MFMA layout (r8 mapping). Wave w owns rows
    // [16w,16w+16); lane (m,q) fetches row s_id[a0+m], slice q*8+kt*32.
    // Hown stays in registers; only staged copy goes to LDS for the other
    // wave and for phase G.
    int m = l & 15;
    int q = l >> 4;
    int a0 = w * 16;
    int o0 = 16 - a0;
    int rowg = s_id[a0 + m];
    const _Float16* gp = (const _Float16*)xf + (size_t)rowg * 128 + q * 8;

    halfx8 Hown[4];
#pragma unroll
    for (int kt = 0; kt < 4; ++kt) Hown[kt] = *(const halfx8*)(gp + kt * 32);
#pragma unroll
    for (int kt = 0; kt < 4; ++kt)
        *(halfx8*)&s_rows[a0 + m][kt * 32 + q * 8] = Hown[kt];
    __syncthreads();

    // D: other wave's rows from LDS; own rows from registers.
    halfx8 Hoth[4];
#pragma unroll
    for (int kt = 0; kt < 4; ++kt)
        Hoth[kt] = *(const halfx8*)&s_rows[o0 + m][kt * 32 + q * 8];

    floatx4 accO = (floatx4){0.f, 0.f, 0.f, 0.f};  // G[a0+i][a0+j]
    floatx4 accX = (floatx4){0.f, 0.f, 0.f, 0.f};  // G[a0+i][o0+j]
#pragma unroll
    for (int kt = 0; kt < 4; ++kt) {
        accO = __builtin_amdgcn_mfma_f32_16x16x32_f16(Hown[kt], Hown[kt], accO, 0, 0, 0);
        accX = __builtin_amdgcn_mfma_f32_16x16x32_f16(Hown[kt], Hoth[kt], accX, 0, 0, 0);
    }

    // D2: diagonal from own quadrant (row==col -> d2_aa == 0 exactly)
    if (q == (m >> 2)) {
        s_diag[a0 + m] = accO[m & 3];
    }
    __syncthreads();

    // E: dist[a] = sum over all 32 b of tw[b]*sqrt(d2>0 ? d2 : 0), a in own 16
    {
        float dbO = s_diag[a0 + m];
        float dbX = s_diag[o0 + m];
        float twO = s_tw[a0 + m];
        float twX = s_tw[o0 + m];
#pragma unroll
        for (int r = 0; r < 4; ++r) {
            int a = a0 + q * 4 + r;
            float da = s_diag[a];
            float d2o = da + dbO - 2.0f * accO[r];
            float d2x = da + dbX - 2.0f * accX[r];
            float t0 = (d2o > 0.0f) ? fast_sqrt(d2o) : 0.0f;
            float t1 = (d2x > 0.0f) ? fast_sqrt(d2x) : 0.0f;
            float v = twO * t0 + twX * t1;
            v += __shfl_xor(v, 1);
            v += __shfl_xor(v, 2);
            v += __shfl_xor(v, 4);
            v += __shfl_xor(v, 8);
            if (m == 0) s_dist[a] = v;
        }
    }
    __syncthreads();

    // F: omega = exp(-dist - max(-dist)) * tw, normalized (wave 0 computes)
    if (w == 0) {
        int k32 = l & 31;
        float s = s_dist[k32];
        float mn = s;
        mn = fminf(mn, __shfl_xor(mn, 1));
        mn = fminf(mn, __shfl_xor(mn, 2));
        mn = fminf(mn, __shfl_xor(mn, 4));
        mn = fminf(mn, __shfl_xor(mn, 8));
        mn = fminf(mn, __shfl_xor(mn, 16));
        float e = fast_exp(mn - s) * s_tw[k32];
        float sum = e;
        sum += __shfl_xor(sum, 1);
        sum += __shfl_xor(sum, 2);
        sum += __shfl_xor(sum, 4);
        sum += __shfl_xor(sum, 8);
        sum += __shfl_xor(sum, 16);
        float om = e * fast_rcp(sum);
        if (l < 32) s_omega[l] = om;
    }
    __syncthreads();

    // G: thread t owns output column t; read s_rows[b][t] (2 lanes/bank =
    // free) with broadcast s_omega[b]. One coalesced float store per thread.
    {
        float o = bias[t];
#pragma unroll
        for (int b = 0; b < 32; ++b) {
            o += s_omega[b] * (float)s_rows[b][t];
        }
        outp[(size_t)i * 128 + t] = o;
    }
}

extern "C" void kernel_launch(void* const* d_in, const int* in_sizes, int n_in,
                              void* d_out, int out_size, void* d_ws, size_t ws_size,
                              hipStream_t stream) {
    const float* feat = (const float*)d_in[0];
    const float* ew = (const float*)d_in[1];
    const float* weight = (const float*)d_in[2];
    const float* bias = (const float*)d_in[3];
    const int* nbr = (const int*)d_in[4];
    float* outp = (float*)d_out;
    int n = in_sizes[0] / NNODE_DIN;  // 50000

    unsigned short* xf = (unsigned short*)d_ws;            // n x 128 fp16
    unsigned short* wth = xf + (size_t)n * NNODE_DOUT;     // 2048 frags x 16B
    unsigned short* wtl = wth + 2048 * 8;

    hipLaunchKernelGGL(k0_wprep, dim3(8), dim3(256), 0, stream, weight, wth, wtl);
    int grid1 = (n + 15) / 16;
    hipLaunchKernelGGL(k1_mfma, dim3(grid1), dim3(64), 0, stream, feat, wth, wtl, xf, n);
    hipLaunchKernelGGL(k2_conv, dim3(n), dim3(128), 0, stream, ew, nbr, bias, xf, outp, n);
}

// Round 13
// 176.247 us; speedup vs baseline: 1.3279x; 1.0024x over previous
//
#include <hip/hip_runtime.h>
#include <hip/hip_bf16.h>

// Problem constants (match reference)
#define NNODE_DIN 128
#define NNODE_DOUT 128
#define DEG 48
#define TOPK 32

typedef _Float16 halfx8 __attribute__((ext_vector_type(8)));
typedef unsigned short ushortx8 __attribute__((ext_vector_type(8)));
typedef float floatx4 __attribute__((ext_vector_type(4)));

__device__ inline unsigned short f2h(float f) {
    _Float16 h = (_Float16)f;
    return __builtin_bit_cast(unsigned short, h);
}
__device__ inline float h2f(unsigned short u) {
    return (float)__builtin_bit_cast(_Float16, u);
}
// Raw transcendentals: proven correct in rounds 1-11 (absmax unchanged).
__device__ inline float fast_sqrt(float x) {
    float r; asm("v_sqrt_f32 %0, %1" : "=v"(r) : "v"(x)); return r;
}
__device__ inline float fast_exp(float x) {  // e^x, x <= 0 here (no overflow path)
    float t = x * 1.44269504088896341f;
    float r; asm("v_exp_f32 %0, %1" : "=v"(r) : "v"(t)); return r;
}
__device__ inline float fast_rcp(float x) {
    float r; asm("v_rcp_f32 %0, %1" : "=v"(r) : "v"(x)); return r;
}

// ---------------------------------------------------------------------------
// Kernel 0: pre-swizzle W^T into split-FP16 MFMA B-fragments (frozen).
// ---------------------------------------------------------------------------
__global__ __launch_bounds__(256) void k0_wprep(
    const float* __restrict__ w, unsigned short* __restrict__ wth,
    unsigned short* __restrict__ wtl) {
    int tid = blockIdx.x * 256 + threadIdx.x;  // 0..2047
    int lane = tid & 63;
    int kt = (tid >> 6) & 3;
    int nt = tid >> 8;
    int m = lane & 15, q = lane >> 4;
    int nn = nt * 16 + m;
    int k0 = kt * 32 + q * 8;
    ushortx8 uh, ul;
#pragma unroll
    for (int e = 0; e < 8; ++e) {
        float v = w[(size_t)(k0 + e) * 128 + nn];
        unsigned short h = f2h(v);
        uh[e] = h;
        ul[e] = f2h(v - h2f(h));
    }
    *(ushortx8*)(wth + tid * 8) = uh;
    *(ushortx8*)(wtl + tid * 8) = ul;
}

// ---------------------------------------------------------------------------
// Kernel 1: x = feat @ W via split-FP16 MFMA. Round-6 shape (best measured
// residue; round-7 4-wave split regressed it). FROZEN.
// ---------------------------------------------------------------------------
__global__ __launch_bounds__(64, 4) void k1_mfma(
    const float* __restrict__ feat, const unsigned short* __restrict__ wth,
    const unsigned short* __restrict__ wtl, unsigned short* __restrict__ xf,
    int n) {
    __shared__ float s_x[16 * 132];
    int l = threadIdx.x;
    int m = l & 15, q = l >> 4;
    int r0 = blockIdx.x * 16;

    halfx8 ah[4], al[4];
#pragma unroll
    for (int kt = 0; kt < 4; ++kt) {
        float vv[8];
        if (r0 + m < n) {
            const float* src = feat + (size_t)(r0 + m) * 128 + kt * 32 + q * 8;
            float4 v0 = *(const float4*)src;
            float4 v1 = *(const float4*)(src + 4);
            vv[0] = v0.x; vv[1] = v0.y; vv[2] = v0.z; vv[3] = v0.w;
            vv[4] = v1.x; vv[5] = v1.y; vv[6] = v1.z; vv[7] = v1.w;
        } else {
#pragma unroll
            for (int e = 0; e < 8; ++e) vv[e] = 0.0f;
        }
        ushortx8 uh, ul;
#pragma unroll
        for (int e = 0; e < 8; ++e) {
            unsigned short h = f2h(vv[e]);
            uh[e] = h;
            ul[e] = f2h(vv[e] - h2f(h));
        }
        ah[kt] = __builtin_bit_cast(halfx8, uh);
        al[kt] = __builtin_bit_cast(halfx8, ul);
    }

#pragma unroll 2
    for (int nt = 0; nt < 8; ++nt) {
        floatx4 a = (floatx4){0.f, 0.f, 0.f, 0.f};
#pragma unroll
        for (int kt = 0; kt < 4; ++kt) {
            int fo = ((nt * 4 + kt) * 64 + l) * 8;
            halfx8 bh = *(const halfx8*)(wth + fo);
            halfx8 bl = *(const halfx8*)(wtl + fo);
            a = __builtin_amdgcn_mfma_f32_16x16x32_f16(ah[kt], bh, a, 0, 0, 0);
            a = __builtin_amdgcn_mfma_f32_16x16x32_f16(ah[kt], bl, a, 0, 0, 0);
            a = __builtin_amdgcn_mfma_f32_16x16x32_f16(al[kt], bh, a, 0, 0, 0);
        }
#pragma unroll
        for (int r = 0; r < 4; ++r)
            s_x[(q * 4 + r) * 132 + nt * 16 + m] = a[r];
    }
    __syncthreads();

#pragma unroll
    for (int rr = 0; rr < 2; ++rr) {
        int row = rr * 8 + (l >> 3);
        int c0 = (l & 7) * 16;
        if (r0 + row < n) {
            float vv[16];
#pragma unroll
            for (int j = 0; j < 4; ++j) {
                float4 v = *(const float4*)&s_x[row * 132 + c0 + j * 4];
                vv[j * 4 + 0] = v.x; vv[j * 4 + 1] = v.y;
                vv[j * 4 + 2] = v.z; vv[j * 4 + 3] = v.w;
            }
            unsigned u[8];
#pragma unroll
            for (int p = 0; p < 8; ++p) {
                u[p] = (unsigned)f2h(vv[2 * p]) | ((unsigned)f2h(vv[2 * p + 1]) << 16);
            }
            size_t off = (size_t)(r0 + row) * 128 + c0;
            *(uint4*)(xf + off) = make_uint4(u[0], u[1], u[2], u[3]);
            *(uint4*)(xf + off + 8) = make_uint4(u[4], u[5], u[6], u[7]);
        }
    }
}

// ---------------------------------------------------------------------------
// Kernel 2: ROUND-13 = ROUND-11 BODY VERBATIM + the single r10-PROVEN change:
// TOPK WAVE-0-ONLY. Round 12 bundled this with a wave-split G epilogue and
// failed numerics (absmax 2.28); the epilogue change is reverted wholesale
// (bug not identified by inspection -> revert and isolate, per discipline).
// This round removes wave 1's redundant 49-iter readlane rank loop (~220
// VALU wave-slots/node, ~13% of chip VALU work on a VALU-bound kernel:
// r11 measured VALUBusy 85-87% at occupancy 80%).
// ---------------------------------------------------------------------------
__global__ __launch_bounds__(128, 4) void k2_conv(
    const float* __restrict__ ew, const int* __restrict__ nbr,
    const float* __restrict__ bias, const unsigned short* __restrict__ xf,
    float* __restrict__ outp, int n) {
    __shared__ float s_tw[32];
    __shared__ int s_id[32];
    __shared__ float s_diag[32];
    __shared__ float s_dist[32];
    __shared__ float s_omega[32];
    __shared__ _Float16 s_rows[32][136];  // padded stride (r7-proven, ~0 confl)

    int i = blockIdx.x;
    int t = threadIdx.x;
    int w = t >> 6;   // wave 0..1
    int l = t & 63;

    // A+B: register top-k (exact jax.lax.top_k tie semantics), WAVE 0 ONLY
    // (verbatim r10, which passed). Lane j holds candidate j (48 neighbors +
    // self at j=48); rank via readlane broadcasts — zero LDS ops.
    if (w == 0) {
        float wj = -1.0f;  // sentinel for lanes 49-63 (rank >= 49, never written)
        int nbv = 0;
        if (l < DEG) {
            wj = ew[(size_t)i * DEG + l];
            nbv = nbr[(size_t)i * DEG + l];
        } else if (l == DEG) {
            wj = 1.0f;
            nbv = i;
        }
        int rank = 0;
#pragma unroll
        for (int t2 = 0; t2 <= DEG; ++t2) {
            int wti = __builtin_amdgcn_readlane(__builtin_bit_cast(int, wj), t2);
            float wt = __builtin_bit_cast(float, wti);
            rank += ((wt > wj) || ((wt == wj) && (t2 < l))) ? 1 : 0;
        }
        if (l <= DEG && rank < TOPK) {
            s_tw[rank] = wj;
            s_id[rank] = nbv;
        }
    }
    __syncthreads();

    // C: gather in direct MFMA layout (r8 mapping). Wave w owns rows
    // [16w,16w+16); lane (m,q) fetches row s_id[a0+m], slice q*8+kt*32.
    // Hown stays in registers; staged copy to LDS for the other wave + G.
    int m = l & 15;
    int q = l >> 4;
    int a0 = w * 16;
    int o0 = 16 - a0;
    int rowg = s_id[a0 + m];
    const _Float16* gp = (const _Float16*)xf + (size_t)rowg * 128 + q * 8;

    halfx8 Hown[4];
#pragma unroll
    for (int kt = 0; kt < 4; ++kt) Hown[kt] = *(const halfx8*)(gp + kt * 32);
#pragma unroll
    for (int kt = 0; kt < 4; ++kt)
        *(halfx8*)&s_rows[a0 + m][kt * 32 + q * 8] = Hown[kt];
    __syncthreads();

    // D: other wave's rows from LDS; own rows from registers.
    halfx8 Hoth[4];
#pragma unroll
    for (int kt = 0; kt < 4; ++kt)
        Hoth[kt] = *(const halfx8*)&s_rows[o0 + m][kt * 32 + q * 8];

    floatx4 accO = (floatx4){0.f, 0.f, 0.f, 0.f};  // G[a0+i][a0+j]
    floatx4 accX = (floatx4){0.f, 0.f, 0.f, 0.f};  // G[a0+i][o0+j]
#pragma unroll
    for (int kt = 0; kt < 4; ++kt) {
        accO = __builtin_amdgcn_mfma_f32_16x16x32_f16(Hown[kt], Hown[kt], accO, 0, 0, 0);
        accX = __builtin_amdgcn_mfma_f32_16x16x32_f16(Hown[kt], Hoth[kt], accX, 0, 0, 0);
    }

    // D2: diagonal from own quadrant (row==col -> d2_aa == 0 exactly)
    if (q == (m >> 2)) {
        s_diag[a0 + m] = accO[m & 3];
    }
    __syncthreads();

    // E: dist[a] = sum over all 32 b of tw[b]*sqrt(d2>0 ? d2 : 0), a in own 16
    {
        float dbO = s_diag[a0 + m];
        float dbX = s_diag[o0 + m];
        float twO = s_tw[a0 + m];
        float twX = s_tw[o0 + m];
#pragma unroll
        for (int r = 0; r < 4; ++r) {
            int a = a0 + q * 4 + r;
            float da = s_diag[a];
            float d2o = da + dbO - 2.0f * accO[r];
            float d2x = da + dbX - 2.0f * accX[r];
            float t0 = (d2o > 0.0f) ? fast_sqrt(d2o) : 0.0f;
            float t1 = (d2x > 0.0f) ? fast_sqrt(d2x) : 0.0f;
            float v = twO * t0 + twX * t1;
            v += __shfl_xor(v, 1);
            v += __shfl_xor(v, 2);
            v += __shfl_xor(v, 4);
            v += __shfl_xor(v, 8);
            if (m == 0) s_dist[a] = v;
        }
    }
    __syncthreads();

    // F: omega = exp(-dist - max(-dist)) * tw, normalized (wave 0 computes)
    if (w == 0) {
        int k32 = l & 31;
        float s = s_dist[k32];
        float mn = s;
        mn = fminf(mn, __shfl_xor(mn, 1));
        mn = fminf(mn, __shfl_xor(mn, 2));
        mn = fminf(mn, __shfl_xor(mn, 4));
        mn = fminf(mn, __shfl_xor(mn, 8));
        mn = fminf(mn, __shfl_xor(mn, 16));
        float e = fast_exp(mn - s) * s_tw[k32];
        float sum = e;
        sum += __shfl_xor(sum, 1);
        sum += __shfl_xor(sum, 2);
        sum += __shfl_xor(sum, 4);
        sum += __shfl_xor(sum, 8);
        sum += __shfl_xor(sum, 16);
        float om = e * fast_rcp(sum);
        if (l < 32) s_omega[l] = om;
    }
    __syncthreads();

    // G: thread t owns output column t; read s_rows[b][t] (2 lanes/bank =
    // free) with broadcast s_omega[b]. One coalesced float store per thread.
    // (r11 verbatim — the r12 wave-split variant failed numerics, reverted.)
    {
        float o = bias[t];
#pragma unroll
        for (int b = 0; b < 32; ++b) {
            o += s_omega[b] * (float)s_rows[b][t];
        }
        outp[(size_t)i * 128 + t] = o;
    }
}

extern "C" void kernel_launch(void* const* d_in, const int* in_sizes, int n_in,
                              void* d_out, int out_size, void* d_ws, size_t ws_size,
                              hipStream_t stream) {
    const float* feat = (const float*)d_in[0];
    const float* ew = (const float*)d_in[1];
    const float* weight = (const float*)d_in[2];
    const float* bias = (const float*)d_in[3];
    const int* nbr = (const int*)d_in[4];
    float* outp = (float*)d_out;
    int n = in_sizes[0] / NNODE_DIN;  // 50000

    unsigned short* xf = (unsigned short*)d_ws;            // n x 128 fp16
    unsigned short* wth = xf + (size_t)n * NNODE_DOUT;     // 2048 frags x 16B
    unsigned short* wtl = wth + 2048 * 8;

    hipLaunchKernelGGL(k0_wprep, dim3(8), dim3(256), 0, stream, weight, wth, wtl);
    int grid1 = (n + 15) / 16;
    hipLaunchKernelGGL(k1_mfma, dim3(grid1), dim3(64), 0, stream, feat, wth, wtl, xf, n);
    hipLaunchKernelGGL(k2_conv, dim3(n), dim3(128), 0, stream, ew, nbr, bias, xf, outp, n);
}